// Round 12
// baseline (367.433 us; speedup 1.0000x reference)
//
#include <hip/hip_runtime.h>
#include <math.h>

typedef unsigned short u16;
typedef unsigned int   u32;
typedef __attribute__((ext_vector_type(4))) float f32x4;
typedef __attribute__((ext_vector_type(16))) float f32x16;
typedef __attribute__((ext_vector_type(8))) short s16x8;
typedef __attribute__((ext_vector_type(4))) unsigned short u16x4;

#define B_N   2
#define S_N   2048
#define HID_N 1024
#define H_N   8
#define HKV_N 2
#define D_N   256
#define QKVW  5120   // qkv_raw row width: 2048 q | 2048 gate | 512 k | 512 v

__device__ __forceinline__ u16 f2bf(float f) {
  union { float f; u32 u; } x; x.f = f;
  u32 r = x.u + 0x7FFFu + ((x.u >> 16) & 1u);
  return (u16)(r >> 16);
}
__device__ __forceinline__ float bf2f(u16 u) {
  union { u32 u; float f; } x; x.u = ((u32)u) << 16; return x.f;
}
__device__ __forceinline__ u32 pk_bf16(float lo, float hi) {
  u32 r;
  asm("v_cvt_pk_bf16_f32 %0, %1, %2" : "=v"(r) : "v"(lo), "v"(hi));
  return r;
}
__device__ __forceinline__ void gload_lds16(const u16* g, u16* l) {
  __builtin_amdgcn_global_load_lds((const __attribute__((address_space(1))) u32*)g,
                                   (__attribute__((address_space(3))) u32*)l, 16, 0, 0);
}

// ---------------- fused fp32 -> bf16 casts (5 segments) ----------------
#define N4_HS 1048576
#define N4_WQ 1048576
#define N4_WK 131072
#define N4_WV 131072
#define N4_WO 524288
#define N4_TOT (N4_HS + N4_WQ + N4_WK + N4_WV + N4_WO)

__global__ __launch_bounds__(256)
void cast5_kernel(const float* __restrict__ hs, const float* __restrict__ wq,
                  const float* __restrict__ wk, const float* __restrict__ wv,
                  const float* __restrict__ wo, u16* __restrict__ hs_bf,
                  u16* __restrict__ wqkv_bf, u16* __restrict__ wo_bf) {
  int i = blockIdx.x * blockDim.x + threadIdx.x;
  const int stride = gridDim.x * blockDim.x;
  for (; i < N4_TOT; i += stride) {
    const float* src; u16* dst; int k;
    if (i < N4_HS)                         { src = hs; dst = hs_bf; k = i; }
    else if (i < N4_HS + N4_WQ)            { src = wq; dst = wqkv_bf; k = i - N4_HS; }
    else if (i < N4_HS + N4_WQ + N4_WK)    { src = wk; dst = wqkv_bf + 4194304; k = i - (N4_HS + N4_WQ); }
    else if (i < N4_TOT - N4_WO)           { src = wv; dst = wqkv_bf + 4718592; k = i - (N4_HS + N4_WQ + N4_WK); }
    else                                   { src = wo; dst = wo_bf; k = i - (N4_TOT - N4_WO); }
    float4 v = reinterpret_cast<const float4*>(src)[k];
    u16x4 o;
    o.x = f2bf(v.x); o.y = f2bf(v.y); o.z = f2bf(v.z); o.w = f2bf(v.w);
    reinterpret_cast<u16x4*>(dst)[k] = o;
  }
}

// ---------------- RoPE trig table ----------------
__global__ __launch_bounds__(256)
void trig_kernel(const int* __restrict__ pos, float* __restrict__ ct, float* __restrict__ st) {
  int i = blockIdx.x * blockDim.x + threadIdx.x;
  if (i >= S_N * 32) return;
  int s = i >> 5, j = i & 31;
  double inv = exp(-(double)j * (log(1.0e7) / 32.0));
  double ang = (double)pos[s] * inv;
  ct[i] = (float)cos(ang);
  st[i] = (float)sin(ang);
}

// ---------------- bf16 GEMM (r9: BK=64, T2 swizzle, counted vmcnt, XCD remap) ----------------
template <int OUT_BF16>
__global__ __launch_bounds__(256, 2)
void gemm_bt_kernel(const u16* __restrict__ A, const u16* __restrict__ Bw,
                    void* __restrict__ Cout, int M, int N, int K, int bn_per_x) {
  const int x = blockIdx.x & 7;
  const int i0 = blockIdx.x >> 3;
  const int bm = i0 / bn_per_x;
  const int bn = x * bn_per_x + (i0 - bm * bn_per_x);
  const int tid = threadIdx.x;
  const int lane = tid & 63;
  const int wr = tid >> 7;
  const int wc = (tid >> 6) & 1;
  __shared__ u16 sA[2][128 * 64];
  __shared__ u16 sB[2][128 * 64];
  f32x4 acc[4][4] = {};
  const u16* Ab = A + (size_t)(bm << 7) * K;
  const u16* Bb = Bw + (size_t)(bn << 7) * K;
  const int nkt = K >> 6;

  auto stage = [&](int buf, int kt) {
    const int k0 = kt << 6;
#pragma unroll
    for (int i = 0; i < 4; ++i) {
      const int L = i * 256 + tid;
      const int r = L >> 3, s = L & 7;
      gload_lds16(Ab + (size_t)r * K + k0 + ((s ^ (r & 7)) << 3), &sA[buf][L * 8]);
    }
#pragma unroll
    for (int i = 0; i < 4; ++i) {
      const int L = i * 256 + tid;
      const int r = L >> 3, s = L & 7;
      gload_lds16(Bb + (size_t)r * K + k0 + ((s ^ (r & 7)) << 3), &sB[buf][L * 8]);
    }
  };

  stage(0, 0);
  int cur = 0;
  const int ra = (wr << 6) + (lane & 15);
  const int rb = (wc << 6) + (lane & 15);
  const int l4 = (lane >> 4);
  const int sw = lane & 7;
  for (int kt = 0; kt < nkt; ++kt) {
    if (kt + 1 < nkt) {
      stage(cur ^ 1, kt + 1);
      asm volatile("s_waitcnt vmcnt(8)" ::: "memory");
    } else {
      asm volatile("s_waitcnt vmcnt(0)" ::: "memory");
    }
    __builtin_amdgcn_s_barrier();
    const u16* sa = sA[cur];
    const u16* sb = sB[cur];
#pragma unroll
    for (int kk = 0; kk < 2; ++kk) {
      const int sl = ((kk * 4 + l4) ^ sw) << 3;
      s16x8 af[4], bfr[4];
#pragma unroll
      for (int m = 0; m < 4; ++m)
        af[m] = *reinterpret_cast<const s16x8*>(sa + (ra + m * 16) * 64 + sl);
#pragma unroll
      for (int n = 0; n < 4; ++n)
        bfr[n] = *reinterpret_cast<const s16x8*>(sb + (rb + n * 16) * 64 + sl);
#pragma unroll
      for (int m = 0; m < 4; ++m)
#pragma unroll
        for (int n = 0; n < 4; ++n)
          acc[m][n] = __builtin_amdgcn_mfma_f32_16x16x32_bf16(af[m], bfr[n], acc[m][n], 0, 0, 0);
    }
    __builtin_amdgcn_s_barrier();
    cur ^= 1;
  }
  const int row0 = (bm << 7) + (wr << 6) + ((lane >> 4) << 2);
  const int col0 = (bn << 7) + (wc << 6) + (lane & 15);
#pragma unroll
  for (int m = 0; m < 4; ++m)
#pragma unroll
    for (int n = 0; n < 4; ++n)
#pragma unroll
      for (int j = 0; j < 4; ++j) {
        size_t idx = (size_t)(row0 + m * 16 + j) * N + col0 + n * 16;
        if (OUT_BF16) ((u16*)Cout)[idx] = f2bf(acc[m][n][j]);
        else          ((float*)Cout)[idx] = acc[m][n][j];
      }
}

// ---------------- RMSNorm + RoPE for q and k ----------------
__global__ __launch_bounds__(256)
void normrope_kernel(const u16* __restrict__ qkv, const float* __restrict__ qw,
                     const float* __restrict__ kw, const float* __restrict__ ct,
                     const float* __restrict__ st, u16* __restrict__ q_r,
                     u16* __restrict__ k_r) {
  const int lane = threadIdx.x & 63;
  const int row = blockIdx.x * 4 + (threadIdx.x >> 6);
  const int nq = B_N * S_N * H_N;
  const u16* src; u16* dst; const float* w;
  int s;
  if (row < nq) {
    int h = row & 7; int bs = row >> 3; s = bs & (S_N - 1); int b = bs >> 11;
    src = qkv + (size_t)(b * S_N + s) * QKVW + h * 256;
    dst = q_r + ((size_t)(b * H_N + h) * S_N + s) * 256;
    w = qw;
  } else {
    int r2 = row - nq;
    int h = r2 & 1; int bs = r2 >> 1; s = bs & (S_N - 1); int b = bs >> 11;
    src = qkv + (size_t)(b * S_N + s) * QKVW + 4096 + h * 256;
    dst = k_r + ((size_t)(b * HKV_N + h) * S_N + s) * 256;
    w = kw;
  }
  u16x4 xv = *reinterpret_cast<const u16x4*>(src + lane * 4);
  float x0 = bf2f(xv.x), x1 = bf2f(xv.y), x2 = bf2f(xv.z), x3 = bf2f(xv.w);
  float ss = x0 * x0 + x1 * x1 + x2 * x2 + x3 * x3;
#pragma unroll
  for (int off = 1; off < 64; off <<= 1) ss += __shfl_xor(ss, off);
  float rinv = rsqrtf(ss * (1.0f / 256.0f) + 1e-6f);
  float4 wv = *reinterpret_cast<const float4*>(w + lane * 4);
  float y[4] = { x0 * rinv * wv.x, x1 * rinv * wv.y, x2 * rinv * wv.z, x3 * rinv * wv.w };
  float p[4];
  p[0] = __shfl_xor(y[0], 8);
  p[1] = __shfl_xor(y[1], 8);
  p[2] = __shfl_xor(y[2], 8);
  p[3] = __shfl_xor(y[3], 8);
  if (lane < 16) {
    const float sgn = (lane < 8) ? -1.0f : 1.0f;
    const int jb = (lane * 4) & 31;
#pragma unroll
    for (int e = 0; e < 4; ++e) {
      float c = ct[(size_t)s * 32 + jb + e];
      float sn = st[(size_t)s * 32 + jb + e];
      y[e] = y[e] * c + sgn * p[e] * sn;
    }
  }
  u16x4 ov;
  ov.x = f2bf(y[0]); ov.y = f2bf(y[1]); ov.z = f2bf(y[2]); ov.w = f2bf(y[3]);
  *reinterpret_cast<u16x4*>(dst + lane * 4) = ov;
}

// ---------------- V transpose ----------------
__global__ __launch_bounds__(256)
void vtrans_kernel(const u16* __restrict__ qkv, u16* __restrict__ vt) {
  const int bid = blockIdx.x;            // 512
  const int dt = bid & 3;
  const int stile = (bid >> 2) & 31;
  const int bh = bid >> 7;
  const int b = bh >> 1, kvh = bh & 1;
  __shared__ u16 tile[64][68];
  const int t = threadIdx.x;
  const u16* src = qkv + (size_t)(b * S_N + stile * 64) * QKVW + 4608 + kvh * 256 + dt * 64;
#pragma unroll
  for (int i = 0; i < 2; ++i) {
    int sl = i * 32 + (t >> 3);
    int d8 = (t & 7) * 8;
    s16x8 v = *reinterpret_cast<const s16x8*>(src + (size_t)sl * QKVW + d8);
    u16x4 lo = { (u16)v[0], (u16)v[1], (u16)v[2], (u16)v[3] };
    u16x4 hi = { (u16)v[4], (u16)v[5], (u16)v[6], (u16)v[7] };
    *reinterpret_cast<u16x4*>(&tile[sl][d8]) = lo;
    *reinterpret_cast<u16x4*>(&tile[sl][d8 + 4]) = hi;
  }
  __syncthreads();
#pragma unroll
  for (int i = 0; i < 2; ++i) {
    int dl = i * 32 + (t >> 3);
    int s8 = (t & 7) * 8;
    u16 tmp[8];
#pragma unroll
    for (int e = 0; e < 8; ++e) tmp[e] = tile[s8 + e][dl];
    u16x4 lo = { tmp[0], tmp[1], tmp[2], tmp[3] };
    u16x4 hi = { tmp[4], tmp[5], tmp[6], tmp[7] };
    u16* dstp = vt + ((size_t)(bh * 256 + dt * 64 + dl)) * S_N + stile * 64 + s8;
    *reinterpret_cast<u16x4*>(dstp) = lo;
    *reinterpret_cast<u16x4*>(dstp + 4) = hi;
  }
}

// ---------------- flash attention: 32x32x16 MFMA + in-block KV-split ----------------
// 4 waves (256 thr, 2 blocks/CU -> 2 waves/SIMD); wave = 32 q-rows of one head
// x one KV half. waves {0,1}: q-subtiles 0/1, KV half 0; waves {2,3}: same q,
// half 1. KVBLK=32, 32 steps/half. 32x32x16 MFMA halves LDS bytes/FLOP vs
// 16x16x32. Swapped QK^T (lane q = lane&31) -> near-free softmax. Exact LDS
// merge of the two halves at the end. LDS = 72KB.
__global__ __launch_bounds__(256, 2)
void attn_kernel(const u16* __restrict__ q_r, const u16* __restrict__ k_r,
                 const u16* __restrict__ vt, const u16* __restrict__ qkv,
                 u16* __restrict__ act) {
  const int dd = blockIdx.x;             // 0..511
  const int xcd = dd & 7;
  const int idx = dd >> 3;               // 0..63
  const int combo = xcd >> 1;            // b*2+kvh (2 XCDs per combo)
  const int within = (xcd & 1) * 64 + idx;  // 0..127
  const int b = combo >> 1;
  const int kvh = combo & 1;
  const int h = kvh * 4 + (within >> 5);
  const int qtile = within & 31;

  const int tid = threadIdx.x;
  const int lane = tid & 63;
  const int w = tid >> 6;                // 0..3
  const int half = w >> 1;               // KV half
  const int l31 = lane & 31;
  const int l5 = lane >> 5;

  __shared__ u16 smem[36864];            // 72KB
  u16* sK = smem + half * 8192;          // [32 kv][256 d], 5-bit XOR swizzle
  u16* sV = smem + 16384 + half * 8192;  // [256 d][32 kv], slot8^((d&3)<<1)
  u16* sP = smem + 32768 + w * 1024;     // [32 q][32 kv], slot8^((q&3)<<1)

  const int q0 = qtile * 64 + (w & 1) * 32;
  const u16* qb = q_r + ((size_t)(b * H_N + h) * S_N + q0) * 256;
  s16x8 qf[16];                          // B-operand: col q = l31, k = ks*16+l5*8+e
#pragma unroll
  for (int ks = 0; ks < 16; ++ks)
    qf[ks] = *reinterpret_cast<const s16x8*>(qb + (size_t)l31 * 256 + ks * 16 + l5 * 8);

  f32x16 oacc[8] = {};                   // out: row q=(r&3)+8*(r>>2)+4*l5, col d=dt*32+l31
  float mrow = -1e30f, lrow = 0.f;

  const u16* kbase = k_r + (size_t)(b * HKV_N + kvh) * S_N * 256;
  const u16* vbase = vt + (size_t)(b * HKV_N + kvh) * 256 * S_N;
  const int lt = tid & 127;              // thread within KV-group

  auto stage = [&](int step) {
    const int kv0 = half * 1024 + (step << 5);
#pragma unroll
    for (int i = 0; i < 8; ++i) {        // K: 32 rows x 32 slot16
      const int L = i * 128 + lt;
      const int kv = L >> 5, s = L & 31;
      gload_lds16(kbase + (size_t)(kv0 + kv) * 256 + ((s ^ kv) << 3), sK + L * 8);
    }
#pragma unroll
    for (int i = 0; i < 8; ++i) {        // V: 256 rows x 4 slot16
      const int L = i * 128 + lt;
      const int d = L >> 2, s = L & 3;
      gload_lds16(vbase + (size_t)d * S_N + kv0 + ((s ^ (d & 3)) << 3), sV + L * 8);
    }
  };

  const float scale = 0.0625f;  // 1/sqrt(256)
  stage(0);
  asm volatile("s_waitcnt vmcnt(0)" ::: "memory");
  __builtin_amdgcn_s_barrier();

  for (int t = 0; t < 32; ++t) {
    // QK^T (swapped): A = K[32 kv x 16 k], B = Q -> S^T: row kv, col q=l31
    f32x16 sacc = {};
    __builtin_amdgcn_s_setprio(1);
#pragma unroll
    for (int ks = 0; ks < 16; ++ks) {
      s16x8 kf = *reinterpret_cast<const s16x8*>(
          sK + l31 * 256 + (((2 * ks + l5) ^ l31) << 3));
      sacc = __builtin_amdgcn_mfma_f32_32x32x16_bf16(kf, qf[ks], sacc, 0, 0, 0);
    }
    __builtin_amdgcn_s_setprio(0);

    // softmax: lane holds 16 kv-scores for q = l31; partner lane^32 has the rest
    float vmax = sacc[0];
#pragma unroll
    for (int r = 1; r < 16; ++r) vmax = fmaxf(vmax, sacc[r]);
    vmax = fmaxf(vmax, __shfl_xor(vmax, 32));
    if (__any(vmax > mrow)) {
      float mnew = fmaxf(mrow, vmax);
      float alpha = __expf((mrow - mnew) * scale);
      mrow = mnew;
      lrow *= alpha;
#pragma unroll
      for (int r = 0; r < 16; ++r) {
        const int qreg = (r & 3) + 8 * (r >> 2) + 4 * l5;
        float ab = __shfl(alpha, qreg);
#pragma unroll
        for (int dt = 0; dt < 8; ++dt) oacc[dt][r] *= ab;
      }
    }
    const float msc = mrow * scale;
    float p[16];
#pragma unroll
    for (int r = 0; r < 16; ++r) p[r] = __expf(fmaf(sacc[r], scale, -msc));
    float rs = ((p[0] + p[1]) + (p[2] + p[3])) + ((p[4] + p[5]) + (p[6] + p[7]))
             + ((p[8] + p[9]) + (p[10] + p[11])) + ((p[12] + p[13]) + (p[14] + p[15]));
    rs += __shfl_xor(rs, 32);
    lrow += rs;

    // P -> bf16 -> per-wave LDS [32 q][32 kv]; reg r covers kv=(r&3)+8*(r>>2)+4*l5
#pragma unroll
    for (int g = 0; g < 4; ++g) {
      u32 lo = pk_bf16(p[4 * g + 0], p[4 * g + 1]);
      u32 hi = pk_bf16(p[4 * g + 2], p[4 * g + 3]);
      union { u32 wd[2]; u16x4 v; } u;
      u.wd[0] = lo; u.wd[1] = hi;
      const int slot8 = (2 * g + l5) ^ ((l31 & 3) << 1);
      *reinterpret_cast<u16x4*>(sP + l31 * 32 + slot8 * 4) = u.v;
    }
    asm volatile("s_waitcnt lgkmcnt(0)" ::: "memory");
    __builtin_amdgcn_sched_barrier(0);

    // PV: A = P[32 q x 16 kv] (2 slices cached), B = V[16 kv x 32 d]
    s16x8 pa[2];
#pragma unroll
    for (int ks = 0; ks < 2; ++ks)
      pa[ks] = *reinterpret_cast<const s16x8*>(
          sP + l31 * 32 + (((4 * ks + 2 * l5) ^ ((l31 & 3) << 1)) << 2));
    __builtin_amdgcn_s_setprio(1);
#pragma unroll
    for (int dt = 0; dt < 8; ++dt) {
      const int drow = dt * 32 + l31;
#pragma unroll
      for (int ks = 0; ks < 2; ++ks) {
        s16x8 vf = *reinterpret_cast<const s16x8*>(
            sV + drow * 32 + (((4 * ks + 2 * l5) ^ ((l31 & 3) << 1)) << 2));
        oacc[dt] = __builtin_amdgcn_mfma_f32_32x32x16_bf16(pa[ks], vf, oacc[dt], 0, 0, 0);
      }
    }
    __builtin_amdgcn_s_setprio(0);

    __builtin_amdgcn_s_barrier();        // all reads of this tile done
    if (t + 1 < 32) {
      stage(t + 1);
      asm volatile("s_waitcnt vmcnt(0)" ::: "memory");
      __builtin_amdgcn_s_barrier();
    }
  }

  // ---- merge the two KV halves (exact, f32 via LDS) ----
  __syncthreads();
  float* mergeO = (float*)smem;          // [64 q][260] f32 (66560 B)
  float* mlb = (float*)(smem + 33280);   // [4 waves][32 q][2] f32
  if (lane < 32) {
    float2 v2 = { mrow, lrow };
    *reinterpret_cast<float2*>(mlb + (w * 32 + l31) * 2) = v2;
  }
  if (half == 1) {
#pragma unroll
    for (int dt = 0; dt < 8; ++dt)
#pragma unroll
      for (int r = 0; r < 16; ++r) {
        const int qreg = (r & 3) + 8 * (r >> 2) + 4 * l5;
        mergeO[((w & 1) * 32 + qreg) * 260 + dt * 32 + l31] = oacc[dt][r];
      }
  }
  __syncthreads();
  if (half == 0) {
    const float2 ml1 = *reinterpret_cast<const float2*>(mlb + ((w + 2) * 32 + l31) * 2);
    const float M = fmaxf(mrow, ml1.x);
    const float e0 = __expf((mrow - M) * scale);
    const float e1 = __expf((ml1.x - M) * scale);
    const float inv = 1.0f / (lrow * e0 + ml1.y * e1);
    const float w0n = e0 * inv, w1n = e1 * inv;
#pragma unroll
    for (int r = 0; r < 16; ++r) {
      const int qreg = (r & 3) + 8 * (r >> 2) + 4 * l5;
      const float W0 = __shfl(w0n, qreg);
      const float W1 = __shfl(w1n, qreg);
      const int qloc = (w & 1) * 32 + qreg;
      const int srow = qtile * 64 + qloc;
#pragma unroll
      for (int dt = 0; dt < 8; ++dt) {
        const int d = dt * 32 + l31;
        float o = oacc[dt][r] * W0 + mergeO[qloc * 260 + d] * W1;
        float g = bf2f(qkv[(size_t)(b * S_N + srow) * QKVW + 2048 + h * 256 + d]);
        float sg = g / (1.0f + __expf(-g));
        act[(size_t)(b * S_N + srow) * 2048 + h * 256 + d] = f2bf(o * sg);
      }
    }
  }
}

extern "C" void kernel_launch(void* const* d_in, const int* in_sizes, int n_in,
                              void* d_out, int out_size, void* d_ws, size_t ws_size,
                              hipStream_t stream) {
  const float* hs  = (const float*)d_in[0];
  const int*   pos = (const int*)d_in[1];
  const float* Wq  = (const float*)d_in[2];
  const float* Wk  = (const float*)d_in[3];
  const float* Wv  = (const float*)d_in[4];
  const float* Wo  = (const float*)d_in[5];
  const float* qw  = (const float*)d_in[6];
  const float* kw  = (const float*)d_in[7];
  float* out = (float*)d_out;

  char* w8 = (char*)d_ws;
  u16* hs_bf   = (u16*)(w8);                    // 8,388,608 B
  u16* wqkv_bf = (u16*)(w8 + 8388608);          // 10,485,760
  u16* wo_bf   = (u16*)(w8 + 18874368);         // 4,194,304
  u16* qkv_raw = (u16*)(w8 + 23068672);         // 41,943,040
  u16* q_r     = (u16*)(w8 + 65011712);         // 16,777,216
  u16* k_r     = (u16*)(w8 + 81788928);         // 4,194,304
  u16* vt      = (u16*)(w8 + 85983232);         // 4,194,304
  u16* act     = (u16*)(w8 + 90177536);         // 16,777,216
  float* cost  = (float*)(w8 + 106954752);      // 262,144
  float* sint  = (float*)(w8 + 107216896);      // 262,144  -> total 107,479,040

  // fused input casts (hs, Wq, Wk, Wv, Wo -> bf16)
  cast5_kernel<<<2048, 256, 0, stream>>>(hs, Wq, Wk, Wv, Wo, hs_bf, wqkv_bf, wo_bf);

  trig_kernel<<<(S_N * 32) / 256, 256, 0, stream>>>(pos, cost, sint);

  // QKV+gate projection: M=4096, N=5120, K=1024 -> qkv_raw bf16
  gemm_bt_kernel<1><<<1280, 256, 0, stream>>>(hs_bf, wqkv_bf, (void*)qkv_raw,
                                              4096, 5120, 1024, 5);

  // RMSNorm + RoPE (q,k); V transpose
  normrope_kernel<<<(B_N * S_N * (H_N + HKV_N)) / 4, 256, 0, stream>>>(
      qkv_raw, qw, kw, cost, sint, q_r, k_r);
  vtrans_kernel<<<512, 256, 0, stream>>>(qkv_raw, vt);

  // attention + gating -> act bf16 (grid 512, 4 waves, 32x32 MFMA, KV-split)
  attn_kernel<<<512, 256, 0, stream>>>(q_r, k_r, vt, qkv_raw, act);

  // output projection: M=4096, N=1024, K=2048 -> d_out fp32
  gemm_bt_kernel<0><<<256, 256, 0, stream>>>(act, wo_bf, (void*)out,
                                             4096, 1024, 2048, 1);
}

// Round 13
// 236.880 us; speedup vs baseline: 1.5511x; 1.5511x over previous
//
#include <hip/hip_runtime.h>
#include <math.h>

typedef unsigned short u16;
typedef unsigned int   u32;
typedef __attribute__((ext_vector_type(4))) float f32x4;
typedef __attribute__((ext_vector_type(8))) short s16x8;
typedef __attribute__((ext_vector_type(4))) unsigned short u16x4;

#define B_N   2
#define S_N   2048
#define HID_N 1024
#define H_N   8
#define HKV_N 2
#define D_N   256
#define QKVW  5120   // qkv_raw row width: 2048 q | 2048 gate | 512 k | 512 v

__device__ __forceinline__ u16 f2bf(float f) {
  union { float f; u32 u; } x; x.f = f;
  u32 r = x.u + 0x7FFFu + ((x.u >> 16) & 1u);
  return (u16)(r >> 16);
}
__device__ __forceinline__ float bf2f(u16 u) {
  union { u32 u; float f; } x; x.u = ((u32)u) << 16; return x.f;
}
__device__ __forceinline__ u32 pk_bf16(float lo, float hi) {
  u32 r;
  asm("v_cvt_pk_bf16_f32 %0, %1, %2" : "=v"(r) : "v"(lo), "v"(hi));
  return r;
}
__device__ __forceinline__ void gload_lds16(const u16* g, u16* l) {
  __builtin_amdgcn_global_load_lds((const __attribute__((address_space(1))) u32*)g,
                                   (__attribute__((address_space(3))) u32*)l, 16, 0, 0);
}

// ---------------- fused fp32 -> bf16 casts (5 segments) ----------------
#define N4_HS 1048576
#define N4_WQ 1048576
#define N4_WK 131072
#define N4_WV 131072
#define N4_WO 524288
#define N4_TOT (N4_HS + N4_WQ + N4_WK + N4_WV + N4_WO)

__global__ __launch_bounds__(256)
void cast5_kernel(const float* __restrict__ hs, const float* __restrict__ wq,
                  const float* __restrict__ wk, const float* __restrict__ wv,
                  const float* __restrict__ wo, u16* __restrict__ hs_bf,
                  u16* __restrict__ wqkv_bf, u16* __restrict__ wo_bf) {
  int i = blockIdx.x * blockDim.x + threadIdx.x;
  const int stride = gridDim.x * blockDim.x;
  for (; i < N4_TOT; i += stride) {
    const float* src; u16* dst; int k;
    if (i < N4_HS)                         { src = hs; dst = hs_bf; k = i; }
    else if (i < N4_HS + N4_WQ)            { src = wq; dst = wqkv_bf; k = i - N4_HS; }
    else if (i < N4_HS + N4_WQ + N4_WK)    { src = wk; dst = wqkv_bf + 4194304; k = i - (N4_HS + N4_WQ); }
    else if (i < N4_TOT - N4_WO)           { src = wv; dst = wqkv_bf + 4718592; k = i - (N4_HS + N4_WQ + N4_WK); }
    else                                   { src = wo; dst = wo_bf; k = i - (N4_TOT - N4_WO); }
    float4 v = reinterpret_cast<const float4*>(src)[k];
    u16x4 o;
    o.x = f2bf(v.x); o.y = f2bf(v.y); o.z = f2bf(v.z); o.w = f2bf(v.w);
    reinterpret_cast<u16x4*>(dst)[k] = o;
  }
}

// ---------------- RoPE trig table ----------------
__global__ __launch_bounds__(256)
void trig_kernel(const int* __restrict__ pos, float* __restrict__ ct, float* __restrict__ st) {
  int i = blockIdx.x * blockDim.x + threadIdx.x;
  if (i >= S_N * 32) return;
  int s = i >> 5, j = i & 31;
  double inv = exp(-(double)j * (log(1.0e7) / 32.0));
  double ang = (double)pos[s] * inv;
  ct[i] = (float)cos(ang);
  st[i] = (float)sin(ang);
}

// ---------------- bf16 GEMM 256x256 tile (GEMM1) ----------------
// 8 waves (512 thr, 2x4), per-wave 128x64 output (8x4 fragments). LDS reads
// per MFMA drop 25% vs the 128^2 tile (12 reads / 32 MFMA). BK=64, r9 XOR
// swizzle, counted vmcnt(8) dbuf, 128KB LDS -> 1 block/CU (2 waves/SIMD).
// XCD remap: grid 320 = 8 xcd x (2 bm x 20 bn), bijective.
__global__ __launch_bounds__(512, 2)
void gemm256_kernel(const u16* __restrict__ A, const u16* __restrict__ Bw,
                    u16* __restrict__ Cout, int M, int N, int K) {
  const int xcd = blockIdx.x & 7;
  const int i0 = blockIdx.x >> 3;        // 0..39
  const int bm = xcd + 8 * (i0 / 20);    // 0..15
  const int bn = i0 % 20;                // 0..19
  const int tid = threadIdx.x;
  const int lane = tid & 63;
  const int wid = tid >> 6;
  const int wm = wid >> 2;               // 0..1
  const int wn = wid & 3;                // 0..3
  const int l15 = lane & 15;
  const int l4 = lane >> 4;
  __shared__ u16 sA[2][256 * 64];
  __shared__ u16 sB[2][256 * 64];
  f32x4 acc[8][4] = {};
  const u16* Ab = A + (size_t)(bm << 8) * K;
  const u16* Bb = Bw + (size_t)(bn << 8) * K;
  const int nkt = K >> 6;

  auto stage = [&](int buf, int kt) {
    const int k0 = kt << 6;
#pragma unroll
    for (int i = 0; i < 4; ++i) {
      const int L = i * 512 + tid;
      const int r = L >> 3, s = L & 7;
      gload_lds16(Ab + (size_t)r * K + k0 + ((s ^ (r & 7)) << 3), &sA[buf][L * 8]);
    }
#pragma unroll
    for (int i = 0; i < 4; ++i) {
      const int L = i * 512 + tid;
      const int r = L >> 3, s = L & 7;
      gload_lds16(Bb + (size_t)r * K + k0 + ((s ^ (r & 7)) << 3), &sB[buf][L * 8]);
    }
  };

  stage(0, 0);
  int cur = 0;
  const int swz = l15 & 7;
  for (int kt = 0; kt < nkt; ++kt) {
    if (kt + 1 < nkt) {
      stage(cur ^ 1, kt + 1);                           // 8 loads in flight
      asm volatile("s_waitcnt vmcnt(8)" ::: "memory");  // current tile landed
    } else {
      asm volatile("s_waitcnt vmcnt(0)" ::: "memory");
    }
    __builtin_amdgcn_s_barrier();
    const u16* sa = &sA[cur][(wm << 7) * 64];
    const u16* sb = &sB[cur][(wn << 6) * 64];
#pragma unroll
    for (int sl = 0; sl < 2; ++sl) {
      const int slot = ((sl * 4 + l4) ^ swz) << 3;
      s16x8 af[8], bf4[4];
#pragma unroll
      for (int m = 0; m < 8; ++m)
        af[m] = *reinterpret_cast<const s16x8*>(sa + (m * 16 + l15) * 64 + slot);
#pragma unroll
      for (int n = 0; n < 4; ++n)
        bf4[n] = *reinterpret_cast<const s16x8*>(sb + (n * 16 + l15) * 64 + slot);
      __builtin_amdgcn_s_setprio(1);
#pragma unroll
      for (int m = 0; m < 8; ++m)
#pragma unroll
        for (int n = 0; n < 4; ++n)
          acc[m][n] = __builtin_amdgcn_mfma_f32_16x16x32_bf16(af[m], bf4[n], acc[m][n], 0, 0, 0);
      __builtin_amdgcn_s_setprio(0);
    }
    __builtin_amdgcn_s_barrier();
    cur ^= 1;
  }
  const int row0 = (bm << 8) + (wm << 7) + (l4 << 2);
  const int col0 = (bn << 8) + (wn << 6) + l15;
#pragma unroll
  for (int m = 0; m < 8; ++m)
#pragma unroll
    for (int n = 0; n < 4; ++n)
#pragma unroll
      for (int j = 0; j < 4; ++j)
        Cout[(size_t)(row0 + m * 16 + j) * N + col0 + n * 16] = f2bf(acc[m][n][j]);
}

// ---------------- bf16 GEMM 128x128 (GEMM2; r9 verified) ----------------
template <int OUT_BF16>
__global__ __launch_bounds__(256, 2)
void gemm_bt_kernel(const u16* __restrict__ A, const u16* __restrict__ Bw,
                    void* __restrict__ Cout, int M, int N, int K, int bn_per_x) {
  const int x = blockIdx.x & 7;
  const int i0 = blockIdx.x >> 3;
  const int bm = i0 / bn_per_x;
  const int bn = x * bn_per_x + (i0 - bm * bn_per_x);
  const int tid = threadIdx.x;
  const int lane = tid & 63;
  const int wr = tid >> 7;
  const int wc = (tid >> 6) & 1;
  __shared__ u16 sA[2][128 * 64];
  __shared__ u16 sB[2][128 * 64];
  f32x4 acc[4][4] = {};
  const u16* Ab = A + (size_t)(bm << 7) * K;
  const u16* Bb = Bw + (size_t)(bn << 7) * K;
  const int nkt = K >> 6;

  auto stage = [&](int buf, int kt) {
    const int k0 = kt << 6;
#pragma unroll
    for (int i = 0; i < 4; ++i) {
      const int L = i * 256 + tid;
      const int r = L >> 3, s = L & 7;
      gload_lds16(Ab + (size_t)r * K + k0 + ((s ^ (r & 7)) << 3), &sA[buf][L * 8]);
    }
#pragma unroll
    for (int i = 0; i < 4; ++i) {
      const int L = i * 256 + tid;
      const int r = L >> 3, s = L & 7;
      gload_lds16(Bb + (size_t)r * K + k0 + ((s ^ (r & 7)) << 3), &sB[buf][L * 8]);
    }
  };

  stage(0, 0);
  int cur = 0;
  const int ra = (wr << 6) + (lane & 15);
  const int rb = (wc << 6) + (lane & 15);
  const int l4 = (lane >> 4);
  const int sw = lane & 7;
  for (int kt = 0; kt < nkt; ++kt) {
    if (kt + 1 < nkt) {
      stage(cur ^ 1, kt + 1);
      asm volatile("s_waitcnt vmcnt(8)" ::: "memory");
    } else {
      asm volatile("s_waitcnt vmcnt(0)" ::: "memory");
    }
    __builtin_amdgcn_s_barrier();
    const u16* sa = sA[cur];
    const u16* sb = sB[cur];
#pragma unroll
    for (int kk = 0; kk < 2; ++kk) {
      const int sl = ((kk * 4 + l4) ^ sw) << 3;
      s16x8 af[4], bfr[4];
#pragma unroll
      for (int m = 0; m < 4; ++m)
        af[m] = *reinterpret_cast<const s16x8*>(sa + (ra + m * 16) * 64 + sl);
#pragma unroll
      for (int n = 0; n < 4; ++n)
        bfr[n] = *reinterpret_cast<const s16x8*>(sb + (rb + n * 16) * 64 + sl);
#pragma unroll
      for (int m = 0; m < 4; ++m)
#pragma unroll
        for (int n = 0; n < 4; ++n)
          acc[m][n] = __builtin_amdgcn_mfma_f32_16x16x32_bf16(af[m], bfr[n], acc[m][n], 0, 0, 0);
    }
    __builtin_amdgcn_s_barrier();
    cur ^= 1;
  }
  const int row0 = (bm << 7) + (wr << 6) + ((lane >> 4) << 2);
  const int col0 = (bn << 7) + (wc << 6) + (lane & 15);
#pragma unroll
  for (int m = 0; m < 4; ++m)
#pragma unroll
    for (int n = 0; n < 4; ++n)
#pragma unroll
      for (int j = 0; j < 4; ++j) {
        size_t idx = (size_t)(row0 + m * 16 + j) * N + col0 + n * 16;
        if (OUT_BF16) ((u16*)Cout)[idx] = f2bf(acc[m][n][j]);
        else          ((float*)Cout)[idx] = acc[m][n][j];
      }
}

// ---------------- RMSNorm + RoPE for q and k ----------------
__global__ __launch_bounds__(256)
void normrope_kernel(const u16* __restrict__ qkv, const float* __restrict__ qw,
                     const float* __restrict__ kw, const float* __restrict__ ct,
                     const float* __restrict__ st, u16* __restrict__ q_r,
                     u16* __restrict__ k_r) {
  const int lane = threadIdx.x & 63;
  const int row = blockIdx.x * 4 + (threadIdx.x >> 6);
  const int nq = B_N * S_N * H_N;
  const u16* src; u16* dst; const float* w;
  int s;
  if (row < nq) {
    int h = row & 7; int bs = row >> 3; s = bs & (S_N - 1); int b = bs >> 11;
    src = qkv + (size_t)(b * S_N + s) * QKVW + h * 256;
    dst = q_r + ((size_t)(b * H_N + h) * S_N + s) * 256;
    w = qw;
  } else {
    int r2 = row - nq;
    int h = r2 & 1; int bs = r2 >> 1; s = bs & (S_N - 1); int b = bs >> 11;
    src = qkv + (size_t)(b * S_N + s) * QKVW + 4096 + h * 256;
    dst = k_r + ((size_t)(b * HKV_N + h) * S_N + s) * 256;
    w = kw;
  }
  u16x4 xv = *reinterpret_cast<const u16x4*>(src + lane * 4);
  float x0 = bf2f(xv.x), x1 = bf2f(xv.y), x2 = bf2f(xv.z), x3 = bf2f(xv.w);
  float ss = x0 * x0 + x1 * x1 + x2 * x2 + x3 * x3;
#pragma unroll
  for (int off = 1; off < 64; off <<= 1) ss += __shfl_xor(ss, off);
  float rinv = rsqrtf(ss * (1.0f / 256.0f) + 1e-6f);
  float4 wv = *reinterpret_cast<const float4*>(w + lane * 4);
  float y[4] = { x0 * rinv * wv.x, x1 * rinv * wv.y, x2 * rinv * wv.z, x3 * rinv * wv.w };
  float p[4];
  p[0] = __shfl_xor(y[0], 8);
  p[1] = __shfl_xor(y[1], 8);
  p[2] = __shfl_xor(y[2], 8);
  p[3] = __shfl_xor(y[3], 8);
  if (lane < 16) {
    const float sgn = (lane < 8) ? -1.0f : 1.0f;
    const int jb = (lane * 4) & 31;
#pragma unroll
    for (int e = 0; e < 4; ++e) {
      float c = ct[(size_t)s * 32 + jb + e];
      float sn = st[(size_t)s * 32 + jb + e];
      y[e] = y[e] * c + sgn * p[e] * sn;
    }
  }
  u16x4 ov;
  ov.x = f2bf(y[0]); ov.y = f2bf(y[1]); ov.z = f2bf(y[2]); ov.w = f2bf(y[3]);
  *reinterpret_cast<u16x4*>(dst + lane * 4) = ov;
}

// ---------------- V transpose ----------------
__global__ __launch_bounds__(256)
void vtrans_kernel(const u16* __restrict__ qkv, u16* __restrict__ vt) {
  const int bid = blockIdx.x;            // 512
  const int dt = bid & 3;
  const int stile = (bid >> 2) & 31;
  const int bh = bid >> 7;
  const int b = bh >> 1, kvh = bh & 1;
  __shared__ u16 tile[64][68];
  const int t = threadIdx.x;
  const u16* src = qkv + (size_t)(b * S_N + stile * 64) * QKVW + 4608 + kvh * 256 + dt * 64;
#pragma unroll
  for (int i = 0; i < 2; ++i) {
    int sl = i * 32 + (t >> 3);
    int d8 = (t & 7) * 8;
    s16x8 v = *reinterpret_cast<const s16x8*>(src + (size_t)sl * QKVW + d8);
    u16x4 lo = { (u16)v[0], (u16)v[1], (u16)v[2], (u16)v[3] };
    u16x4 hi = { (u16)v[4], (u16)v[5], (u16)v[6], (u16)v[7] };
    *reinterpret_cast<u16x4*>(&tile[sl][d8]) = lo;
    *reinterpret_cast<u16x4*>(&tile[sl][d8 + 4]) = hi;
  }
  __syncthreads();
#pragma unroll
  for (int i = 0; i < 2; ++i) {
    int dl = i * 32 + (t >> 3);
    int s8 = (t & 7) * 8;
    u16 tmp[8];
#pragma unroll
    for (int e = 0; e < 8; ++e) tmp[e] = tile[s8 + e][dl];
    u16x4 lo = { tmp[0], tmp[1], tmp[2], tmp[3] };
    u16x4 hi = { tmp[4], tmp[5], tmp[6], tmp[7] };
    u16* dstp = vt + ((size_t)(bh * 256 + dt * 64 + dl)) * S_N + stile * 64 + s8;
    *reinterpret_cast<u16x4*>(dstp) = lo;
    *reinterpret_cast<u16x4*>(dstp + 4) = hi;
  }
}

// ---------------- flash attention + silu gating (r9 verified, 112us) ----------------
__global__ __launch_bounds__(512, 2)
void attn_kernel(const u16* __restrict__ q_r, const u16* __restrict__ k_r,
                 const u16* __restrict__ vt, const u16* __restrict__ qkv,
                 u16* __restrict__ act) {
  const int dd = blockIdx.x;             // 0..255
  const int xcd = dd & 7;
  const int idx = dd >> 3;               // 0..31
  const int combo = xcd >> 1;            // b*2+kvh
  const int within = (xcd & 1) * 32 + idx;
  const int b = combo >> 1;
  const int kvh = combo & 1;
  const int h = kvh * 4 + (within >> 4);
  const int qt = within & 15;

  const int tid = threadIdx.x;
  const int lane = tid & 63;
  const int wv = tid >> 6;               // 0..7
  const int l15 = lane & 15;
  const int l4 = lane >> 4;

  __shared__ u16 sK[2][64 * 256];        // [kv][d], swizzled 16B slots
  __shared__ u16 sVt[2][256 * 64];       // [d][kv], swizzled
  __shared__ u16 sP[8][16 * 64];         // per-wave P tile, swizzled (8B slots)

  const int q0 = qt * 128 + wv * 16;
  const u16* qb = q_r + ((size_t)(b * H_N + h) * S_N + q0) * 256;
  s16x8 qf[8];
#pragma unroll
  for (int kk = 0; kk < 8; ++kk)
    qf[kk] = *reinterpret_cast<const s16x8*>(qb + (size_t)l15 * 256 + kk * 32 + l4 * 8);

  f32x4 oacc[16] = {};
  float mrow = -1e30f;
  float lrow = 0.f;

  const u16* kbase = k_r + ((size_t)(b * HKV_N + kvh) * S_N) * 256;
  const u16* vbase = vt + ((size_t)(b * HKV_N + kvh) * 256) * S_N;

  const int krow_b = tid >> 5;           // 0..15
  const int kp = tid & 31;
  const int vrow_b = tid >> 3;           // 0..63
  const int vp = tid & 7;

  auto stageKV = [&](int buf, int step) {
    const int kv0 = step << 6;
#pragma unroll
    for (int i = 0; i < 4; ++i) {
      const int krow = i * 16 + krow_b;
      gload_lds16(kbase + (size_t)(kv0 + krow) * 256 + ((kp ^ (krow_b & 7)) << 3),
                  &sK[buf][i * 4096 + tid * 8]);
    }
#pragma unroll
    for (int i = 0; i < 4; ++i) {
      const int vrow = i * 64 + vrow_b;
      gload_lds16(vbase + (size_t)vrow * S_N + kv0 + ((vp ^ (vrow_b & 7)) << 3),
                  &sVt[buf][i * 4096 + tid * 8]);
    }
  };

  stageKV(0, 0);
  int cur = 0;
  const float scale = 0.0625f;  // 1/sqrt(256)
  const int sw = l15 & 7;
  const int swp = l15 & 14;              // even XOR for 8B P slots
  for (int step = 0; step < 32; ++step) {
    asm volatile("s_waitcnt vmcnt(0)" ::: "memory");
    __builtin_amdgcn_s_barrier();
    if (step + 1 < 32) stageKV(cur ^ 1, step + 1);
    const u16* ktile = sK[cur];
    const u16* vtile = sVt[cur];

    // swapped QK^T: sacc[g] = S^T tile; lane holds q-col = l15,
    // kv-rows = g*16 + l4*4 + j
    f32x4 sacc[4] = {};
#pragma unroll
    for (int kk = 0; kk < 8; ++kk) {
      const int slot = kk * 4 + l4;
#pragma unroll
      for (int g = 0; g < 4; ++g) {
        s16x8 kf = *reinterpret_cast<const s16x8*>(
            ktile + (g * 16 + l15) * 256 + ((slot ^ sw) << 3));
        sacc[g] = __builtin_amdgcn_mfma_f32_16x16x32_bf16(kf, qf[kk], sacc[g], 0, 0, 0);
      }
    }

    // in-register row softmax (q = l15): per-lane reduce + 2 shuffles
    float vmax = sacc[0][0];
#pragma unroll
    for (int g = 0; g < 4; ++g)
#pragma unroll
      for (int j = 0; j < 4; ++j) vmax = fmaxf(vmax, sacc[g][j]);
    vmax = fmaxf(vmax, __shfl_xor(vmax, 16));
    vmax = fmaxf(vmax, __shfl_xor(vmax, 32));
    if (__any(vmax > mrow)) {
      float mnew = fmaxf(mrow, vmax);
      float alpha = __expf((mrow - mnew) * scale);
      mrow = mnew;
      lrow *= alpha;
      float ab[4];
#pragma unroll
      for (int j = 0; j < 4; ++j) ab[j] = __shfl(alpha, l4 * 4 + j);
#pragma unroll
      for (int nf = 0; nf < 16; ++nf) {
        oacc[nf][0] *= ab[0]; oacc[nf][1] *= ab[1];
        oacc[nf][2] *= ab[2]; oacc[nf][3] *= ab[3];
      }
    }
    const float msc = mrow * scale;
    float p[16];
#pragma unroll
    for (int g = 0; g < 4; ++g)
#pragma unroll
      for (int j = 0; j < 4; ++j)
        p[g * 4 + j] = __expf(fmaf(sacc[g][j], scale, -msc));
    float r = ((p[0] + p[1]) + (p[2] + p[3])) + ((p[4] + p[5]) + (p[6] + p[7]))
            + ((p[8] + p[9]) + (p[10] + p[11])) + ((p[12] + p[13]) + (p[14] + p[15]));
    r += __shfl_xor(r, 16);
    r += __shfl_xor(r, 32);
    lrow += r;

    // P pack (bf16 pairs) -> 4 x ds_write_b64, conflict-free swizzle
    u16* pl = &sP[wv][0];
#pragma unroll
    for (int g = 0; g < 4; ++g) {
      u32 lo = pk_bf16(p[g * 4 + 0], p[g * 4 + 1]);
      u32 hi = pk_bf16(p[g * 4 + 2], p[g * 4 + 3]);
      union { u32 w[2]; u16x4 v; } u;
      u.w[0] = lo; u.w[1] = hi;
      *reinterpret_cast<u16x4*>(pl + l15 * 64 + (((g * 4 + l4) ^ swp) << 2)) = u.v;
    }
    asm volatile("s_waitcnt lgkmcnt(0)" ::: "memory");
    __builtin_amdgcn_sched_barrier(0);

    // PV: O[q][d] += P[q][kv] @ V[kv][d]
#pragma unroll
    for (int c = 0; c < 2; ++c) {
      s16x8 paf = *reinterpret_cast<const s16x8*>(
          pl + l15 * 64 + (((c * 8 + l4 * 2) ^ swp) << 2));
#pragma unroll
      for (int nf = 0; nf < 16; ++nf) {
        s16x8 vf = *reinterpret_cast<const s16x8*>(
            vtile + (nf * 16 + l15) * 64 + (((c * 4 + l4) ^ sw) << 3));
        oacc[nf] = __builtin_amdgcn_mfma_f32_16x16x32_bf16(paf, vf, oacc[nf], 0, 0, 0);
      }
    }
    cur ^= 1;
  }

  // epilogue: O/l, silu(gate), write activation for final GEMM
  float invl = 1.0f / lrow;
  float ib[4];
#pragma unroll
  for (int j = 0; j < 4; ++j) ib[j] = __shfl(invl, l4 * 4 + j);
#pragma unroll
  for (int nf = 0; nf < 16; ++nf) {
#pragma unroll
    for (int j = 0; j < 4; ++j) {
      const int srow = q0 + l4 * 4 + j;
      const int d = nf * 16 + l15;
      float o = oacc[nf][j] * ib[j];
      float g = bf2f(qkv[(size_t)(b * S_N + srow) * QKVW + 2048 + h * 256 + d]);
      float sg = g / (1.0f + __expf(-g));
      act[(size_t)(b * S_N + srow) * 2048 + h * 256 + d] = f2bf(o * sg);
    }
  }
}

extern "C" void kernel_launch(void* const* d_in, const int* in_sizes, int n_in,
                              void* d_out, int out_size, void* d_ws, size_t ws_size,
                              hipStream_t stream) {
  const float* hs  = (const float*)d_in[0];
  const int*   pos = (const int*)d_in[1];
  const float* Wq  = (const float*)d_in[2];
  const float* Wk  = (const float*)d_in[3];
  const float* Wv  = (const float*)d_in[4];
  const float* Wo  = (const float*)d_in[5];
  const float* qw  = (const float*)d_in[6];
  const float* kw  = (const float*)d_in[7];
  float* out = (float*)d_out;

  char* w8 = (char*)d_ws;
  u16* hs_bf   = (u16*)(w8);                    // 8,388,608 B
  u16* wqkv_bf = (u16*)(w8 + 8388608);          // 10,485,760
  u16* wo_bf   = (u16*)(w8 + 18874368);         // 4,194,304
  u16* qkv_raw = (u16*)(w8 + 23068672);         // 41,943,040
  u16* q_r     = (u16*)(w8 + 65011712);         // 16,777,216
  u16* k_r     = (u16*)(w8 + 81788928);         // 4,194,304
  u16* vt      = (u16*)(w8 + 85983232);         // 4,194,304
  u16* act     = (u16*)(w8 + 90177536);         // 16,777,216
  float* cost  = (float*)(w8 + 106954752);      // 262,144
  float* sint  = (float*)(w8 + 107216896);      // 262,144  -> total 107,479,040

  // fused input casts (hs, Wq, Wk, Wv, Wo -> bf16)
  cast5_kernel<<<2048, 256, 0, stream>>>(hs, Wq, Wk, Wv, Wo, hs_bf, wqkv_bf, wo_bf);

  trig_kernel<<<(S_N * 32) / 256, 256, 0, stream>>>(pos, cost, sint);

  // QKV+gate projection: M=4096, N=5120, K=1024 -> qkv_raw bf16 (256^2 tile)
  gemm256_kernel<<<320, 512, 0, stream>>>(hs_bf, wqkv_bf, qkv_raw, 4096, 5120, 1024);

  // RMSNorm + RoPE (q,k); V transpose
  normrope_kernel<<<(B_N * S_N * (H_N + HKV_N)) / 4, 256, 0, stream>>>(
      qkv_raw, qw, kw, cost, sint, q_r, k_r);
  vtrans_kernel<<<512, 256, 0, stream>>>(qkv_raw, vt);

  // attention + gating -> act bf16 (r9 verified structure)
  attn_kernel<<<256, 512, 0, stream>>>(q_r, k_r, vt, qkv_raw, act);

  // output projection: M=4096, N=1024, K=2048 -> d_out fp32
  gemm_bt_kernel<0><<<256, 256, 0, stream>>>(act, wo_bf, (void*)out,
                                             4096, 1024, 2048, 1);
}

// Round 14
// 226.993 us; speedup vs baseline: 1.6187x; 1.0436x over previous
//
#include <hip/hip_runtime.h>
#include <math.h>

typedef unsigned short u16;
typedef unsigned int   u32;
typedef __attribute__((ext_vector_type(4))) float f32x4;
typedef __attribute__((ext_vector_type(8))) short s16x8;
typedef __attribute__((ext_vector_type(4))) unsigned short u16x4;

#define B_N   2
#define S_N   2048
#define HID_N 1024
#define H_N   8
#define HKV_N 2
#define D_N   256
#define QKVW  5120   // qkv_raw row width: 2048 q | 2048 gate | 512 k | 512 v

__device__ __forceinline__ u16 f2bf(float f) {
  union { float f; u32 u; } x; x.f = f;
  u32 r = x.u + 0x7FFFu + ((x.u >> 16) & 1u);
  return (u16)(r >> 16);
}
__device__ __forceinline__ float bf2f(u16 u) {
  union { u32 u; float f; } x; x.u = ((u32)u) << 16; return x.f;
}
__device__ __forceinline__ u32 pk_bf16(float lo, float hi) {
  u32 r;
  asm("v_cvt_pk_bf16_f32 %0, %1, %2" : "=v"(r) : "v"(lo), "v"(hi));
  return r;
}
__device__ __forceinline__ void gload_lds16(const u16* g, u16* l) {
  __builtin_amdgcn_global_load_lds((const __attribute__((address_space(1))) u32*)g,
                                   (__attribute__((address_space(3))) u32*)l, 16, 0, 0);
}

// ---------------- fused fp32 -> bf16 casts (5 segments) ----------------
#define N4_HS 1048576
#define N4_WQ 1048576
#define N4_WK 131072
#define N4_WV 131072
#define N4_WO 524288
#define N4_TOT (N4_HS + N4_WQ + N4_WK + N4_WV + N4_WO)

__global__ __launch_bounds__(256)
void cast5_kernel(const float* __restrict__ hs, const float* __restrict__ wq,
                  const float* __restrict__ wk, const float* __restrict__ wv,
                  const float* __restrict__ wo, u16* __restrict__ hs_bf,
                  u16* __restrict__ wqkv_bf, u16* __restrict__ wo_bf) {
  int i = blockIdx.x * blockDim.x + threadIdx.x;
  const int stride = gridDim.x * blockDim.x;
  for (; i < N4_TOT; i += stride) {
    const float* src; u16* dst; int k;
    if (i < N4_HS)                         { src = hs; dst = hs_bf; k = i; }
    else if (i < N4_HS + N4_WQ)            { src = wq; dst = wqkv_bf; k = i - N4_HS; }
    else if (i < N4_HS + N4_WQ + N4_WK)    { src = wk; dst = wqkv_bf + 4194304; k = i - (N4_HS + N4_WQ); }
    else if (i < N4_TOT - N4_WO)           { src = wv; dst = wqkv_bf + 4718592; k = i - (N4_HS + N4_WQ + N4_WK); }
    else                                   { src = wo; dst = wo_bf; k = i - (N4_TOT - N4_WO); }
    float4 v = reinterpret_cast<const float4*>(src)[k];
    u16x4 o;
    o.x = f2bf(v.x); o.y = f2bf(v.y); o.z = f2bf(v.z); o.w = f2bf(v.w);
    reinterpret_cast<u16x4*>(dst)[k] = o;
  }
}

// ---------------- RoPE trig table ----------------
__global__ __launch_bounds__(256)
void trig_kernel(const int* __restrict__ pos, float* __restrict__ ct, float* __restrict__ st) {
  int i = blockIdx.x * blockDim.x + threadIdx.x;
  if (i >= S_N * 32) return;
  int s = i >> 5, j = i & 31;
  double inv = exp(-(double)j * (log(1.0e7) / 32.0));
  double ang = (double)pos[s] * inv;
  ct[i] = (float)cos(ang);
  st[i] = (float)sin(ang);
}

// ---------------- bf16 GEMM: m97 structure (BK=32, 32KB LDS, high occupancy) ----------------
// 128x128 tile, BK=32, 4 waves, linear LDS (no swizzle — m97 hit 874 TF with
// 1.7e7 conflicts; occupancy 3-4 blocks/CU hides them). Double-buffered,
// vmcnt(0)+barrier loop. XCD remap for L2 residency.
template <int OUT_BF16>
__global__ __launch_bounds__(256, 4)
void gemm_bt_kernel(const u16* __restrict__ A, const u16* __restrict__ Bw,
                    void* __restrict__ Cout, int M, int N, int K, int bn_per_x) {
  const int x = blockIdx.x & 7;
  const int i0 = blockIdx.x >> 3;
  const int bm = i0 / bn_per_x;
  const int bn = x * bn_per_x + (i0 - bm * bn_per_x);
  const int tid = threadIdx.x;
  const int lane = tid & 63;
  const int wr = tid >> 7;
  const int wc = (tid >> 6) & 1;
  __shared__ u16 sA[2][128 * 32];
  __shared__ u16 sB[2][128 * 32];
  f32x4 acc[4][4] = {};
  const u16* Ab = A + (size_t)(bm << 7) * K;
  const u16* Bb = Bw + (size_t)(bn << 7) * K;
  const int r_st = tid >> 2;
  const int c_st = (tid & 3) * 8;
  const int nkt = K >> 5;

  auto stage = [&](int buf, int kt) {
    const int k0 = kt << 5;
    gload_lds16(Ab + (size_t)r_st * K + k0 + c_st,        &sA[buf][tid * 8]);
    gload_lds16(Ab + (size_t)(r_st + 64) * K + k0 + c_st, &sA[buf][2048 + tid * 8]);
    gload_lds16(Bb + (size_t)r_st * K + k0 + c_st,        &sB[buf][tid * 8]);
    gload_lds16(Bb + (size_t)(r_st + 64) * K + k0 + c_st, &sB[buf][2048 + tid * 8]);
  };

  stage(0, 0);
  int cur = 0;
  const int ra = (wr << 6) + (lane & 15);
  const int rb = (wc << 6) + (lane & 15);
  const int ks = (lane >> 4) << 3;
  for (int kt = 0; kt < nkt; ++kt) {
    asm volatile("s_waitcnt vmcnt(0)" ::: "memory");
    __builtin_amdgcn_s_barrier();
    if (kt + 1 < nkt) stage(cur ^ 1, kt + 1);
    const u16* sa = sA[cur];
    const u16* sb = sB[cur];
    s16x8 af[4], bfr[4];
#pragma unroll
    for (int m = 0; m < 4; ++m) af[m] = *reinterpret_cast<const s16x8*>(sa + (ra + m * 16) * 32 + ks);
#pragma unroll
    for (int n = 0; n < 4; ++n) bfr[n] = *reinterpret_cast<const s16x8*>(sb + (rb + n * 16) * 32 + ks);
#pragma unroll
    for (int m = 0; m < 4; ++m)
#pragma unroll
      for (int n = 0; n < 4; ++n)
        acc[m][n] = __builtin_amdgcn_mfma_f32_16x16x32_bf16(af[m], bfr[n], acc[m][n], 0, 0, 0);
    __builtin_amdgcn_s_barrier();
    cur ^= 1;
  }
  const int row0 = (bm << 7) + (wr << 6) + ((lane >> 4) << 2);
  const int col0 = (bn << 7) + (wc << 6) + (lane & 15);
#pragma unroll
  for (int m = 0; m < 4; ++m)
#pragma unroll
    for (int n = 0; n < 4; ++n)
#pragma unroll
      for (int j = 0; j < 4; ++j) {
        size_t idx = (size_t)(row0 + m * 16 + j) * N + col0 + n * 16;
        if (OUT_BF16) ((u16*)Cout)[idx] = f2bf(acc[m][n][j]);
        else          ((float*)Cout)[idx] = acc[m][n][j];
      }
}

// ---------------- RMSNorm + RoPE for q and k ----------------
__global__ __launch_bounds__(256)
void normrope_kernel(const u16* __restrict__ qkv, const float* __restrict__ qw,
                     const float* __restrict__ kw, const float* __restrict__ ct,
                     const float* __restrict__ st, u16* __restrict__ q_r,
                     u16* __restrict__ k_r) {
  const int lane = threadIdx.x & 63;
  const int row = blockIdx.x * 4 + (threadIdx.x >> 6);
  const int nq = B_N * S_N * H_N;
  const u16* src; u16* dst; const float* w;
  int s;
  if (row < nq) {
    int h = row & 7; int bs = row >> 3; s = bs & (S_N - 1); int b = bs >> 11;
    src = qkv + (size_t)(b * S_N + s) * QKVW + h * 256;
    dst = q_r + ((size_t)(b * H_N + h) * S_N + s) * 256;
    w = qw;
  } else {
    int r2 = row - nq;
    int h = r2 & 1; int bs = r2 >> 1; s = bs & (S_N - 1); int b = bs >> 11;
    src = qkv + (size_t)(b * S_N + s) * QKVW + 4096 + h * 256;
    dst = k_r + ((size_t)(b * HKV_N + h) * S_N + s) * 256;
    w = kw;
  }
  u16x4 xv = *reinterpret_cast<const u16x4*>(src + lane * 4);
  float x0 = bf2f(xv.x), x1 = bf2f(xv.y), x2 = bf2f(xv.z), x3 = bf2f(xv.w);
  float ss = x0 * x0 + x1 * x1 + x2 * x2 + x3 * x3;
#pragma unroll
  for (int off = 1; off < 64; off <<= 1) ss += __shfl_xor(ss, off);
  float rinv = rsqrtf(ss * (1.0f / 256.0f) + 1e-6f);
  float4 wv = *reinterpret_cast<const float4*>(w + lane * 4);
  float y[4] = { x0 * rinv * wv.x, x1 * rinv * wv.y, x2 * rinv * wv.z, x3 * rinv * wv.w };
  float p[4];
  p[0] = __shfl_xor(y[0], 8);
  p[1] = __shfl_xor(y[1], 8);
  p[2] = __shfl_xor(y[2], 8);
  p[3] = __shfl_xor(y[3], 8);
  if (lane < 16) {
    const float sgn = (lane < 8) ? -1.0f : 1.0f;
    const int jb = (lane * 4) & 31;
#pragma unroll
    for (int e = 0; e < 4; ++e) {
      float c = ct[(size_t)s * 32 + jb + e];
      float sn = st[(size_t)s * 32 + jb + e];
      y[e] = y[e] * c + sgn * p[e] * sn;
    }
  }
  u16x4 ov;
  ov.x = f2bf(y[0]); ov.y = f2bf(y[1]); ov.z = f2bf(y[2]); ov.w = f2bf(y[3]);
  *reinterpret_cast<u16x4*>(dst + lane * 4) = ov;
}

// ---------------- V transpose ----------------
__global__ __launch_bounds__(256)
void vtrans_kernel(const u16* __restrict__ qkv, u16* __restrict__ vt) {
  const int bid = blockIdx.x;            // 512
  const int dt = bid & 3;
  const int stile = (bid >> 2) & 31;
  const int bh = bid >> 7;
  const int b = bh >> 1, kvh = bh & 1;
  __shared__ u16 tile[64][68];
  const int t = threadIdx.x;
  const u16* src = qkv + (size_t)(b * S_N + stile * 64) * QKVW + 4608 + kvh * 256 + dt * 64;
#pragma unroll
  for (int i = 0; i < 2; ++i) {
    int sl = i * 32 + (t >> 3);
    int d8 = (t & 7) * 8;
    s16x8 v = *reinterpret_cast<const s16x8*>(src + (size_t)sl * QKVW + d8);
    u16x4 lo = { (u16)v[0], (u16)v[1], (u16)v[2], (u16)v[3] };
    u16x4 hi = { (u16)v[4], (u16)v[5], (u16)v[6], (u16)v[7] };
    *reinterpret_cast<u16x4*>(&tile[sl][d8]) = lo;
    *reinterpret_cast<u16x4*>(&tile[sl][d8 + 4]) = hi;
  }
  __syncthreads();
#pragma unroll
  for (int i = 0; i < 2; ++i) {
    int dl = i * 32 + (t >> 3);
    int s8 = (t & 7) * 8;
    u16 tmp[8];
#pragma unroll
    for (int e = 0; e < 8; ++e) tmp[e] = tile[s8 + e][dl];
    u16x4 lo = { tmp[0], tmp[1], tmp[2], tmp[3] };
    u16x4 hi = { tmp[4], tmp[5], tmp[6], tmp[7] };
    u16* dstp = vt + ((size_t)(bh * 256 + dt * 64 + dl)) * S_N + stile * 64 + s8;
    *reinterpret_cast<u16x4*>(dstp) = lo;
    *reinterpret_cast<u16x4*>(dstp + 4) = hi;
  }
}

// ---------------- flash attention, cross-step pipelined (r11 verified) ----------------
__global__ __launch_bounds__(512, 2)
void attn_kernel(const u16* __restrict__ q_r, const u16* __restrict__ k_r,
                 const u16* __restrict__ vt, const u16* __restrict__ qkv,
                 u16* __restrict__ act) {
  const int dd = blockIdx.x;             // 0..255
  const int xcd = dd & 7;
  const int idx = dd >> 3;               // 0..31
  const int combo = xcd >> 1;            // b*2+kvh
  const int within = (xcd & 1) * 32 + idx;
  const int b = combo >> 1;
  const int kvh = combo & 1;
  const int h = kvh * 4 + (within >> 4);
  const int qt = within & 15;

  const int tid = threadIdx.x;
  const int lane = tid & 63;
  const int wv = tid >> 6;               // 0..7
  const int l15 = lane & 15;
  const int l4 = lane >> 4;

  __shared__ u16 sK[2][64 * 256];        // [kv][d], swizzled 16B slots (64KB)
  __shared__ u16 sVt[2][256 * 64];       // [d][kv], swizzled (64KB)
  __shared__ u16 sP[8][2][16 * 64];      // per-wave P, dbuf, 8B slots (32KB)

  const int q0 = qt * 128 + wv * 16;
  const u16* qb = q_r + ((size_t)(b * H_N + h) * S_N + q0) * 256;
  s16x8 qf[8];
#pragma unroll
  for (int kk = 0; kk < 8; ++kk)
    qf[kk] = *reinterpret_cast<const s16x8*>(qb + (size_t)l15 * 256 + kk * 32 + l4 * 8);

  f32x4 oacc[16] = {};
  float mrow = -1e30f;
  float lrow = 0.f;

  const u16* kbase = k_r + ((size_t)(b * HKV_N + kvh) * S_N) * 256;
  const u16* vbase = vt + ((size_t)(b * HKV_N + kvh) * 256) * S_N;

  const int krow_b = tid >> 5;           // 0..15
  const int kp = tid & 31;
  const int vrow_b = tid >> 3;           // 0..63
  const int vp = tid & 7;

  auto stageK = [&](int buf, int step) {
    const int kv0 = step << 6;
#pragma unroll
    for (int i = 0; i < 4; ++i) {
      const int krow = i * 16 + krow_b;
      gload_lds16(kbase + (size_t)(kv0 + krow) * 256 + ((kp ^ (krow_b & 7)) << 3),
                  &sK[buf][i * 4096 + tid * 8]);
    }
  };
  auto stageV = [&](int buf, int step) {
    const int kv0 = step << 6;
#pragma unroll
    for (int i = 0; i < 4; ++i) {
      const int vrow = i * 64 + vrow_b;
      gload_lds16(vbase + (size_t)vrow * S_N + kv0 + ((vp ^ (vrow_b & 7)) << 3),
                  &sVt[buf][i * 4096 + tid * 8]);
    }
  };

  const float scale = 0.0625f;  // 1/sqrt(256)
  const int sw = l15 & 7;
  const int swp = l15 & 14;              // even XOR for 8B P slots

  auto computeQK = [&](const u16* ktile, f32x4* sacc) {
#pragma unroll
    for (int kk = 0; kk < 8; ++kk) {
      const int slot = kk * 4 + l4;
#pragma unroll
      for (int g = 0; g < 4; ++g) {
        s16x8 kf = *reinterpret_cast<const s16x8*>(
            ktile + (g * 16 + l15) * 256 + ((slot ^ sw) << 3));
        sacc[g] = __builtin_amdgcn_mfma_f32_16x16x32_bf16(kf, qf[kk], sacc[g], 0, 0, 0);
      }
    }
  };
  float alphaNext = 1.0f;
  int doRescale = 0;
  auto softmaxPack = [&](f32x4* sacc, int pb) {
    float vmax = sacc[0][0];
#pragma unroll
    for (int g = 0; g < 4; ++g)
#pragma unroll
      for (int j = 0; j < 4; ++j) vmax = fmaxf(vmax, sacc[g][j]);
    vmax = fmaxf(vmax, __shfl_xor(vmax, 16));
    vmax = fmaxf(vmax, __shfl_xor(vmax, 32));
    doRescale = __any(vmax > mrow) ? 1 : 0;
    if (doRescale) {
      float mnew = fmaxf(mrow, vmax);
      alphaNext = __expf((mrow - mnew) * scale);
      mrow = mnew;
      lrow *= alphaNext;
    } else {
      alphaNext = 1.0f;
    }
    const float msc = mrow * scale;
    float p[16];
#pragma unroll
    for (int g = 0; g < 4; ++g)
#pragma unroll
      for (int j = 0; j < 4; ++j)
        p[g * 4 + j] = __expf(fmaf(sacc[g][j], scale, -msc));
    float r = ((p[0] + p[1]) + (p[2] + p[3])) + ((p[4] + p[5]) + (p[6] + p[7]))
            + ((p[8] + p[9]) + (p[10] + p[11])) + ((p[12] + p[13]) + (p[14] + p[15]));
    r += __shfl_xor(r, 16);
    r += __shfl_xor(r, 32);
    lrow += r;
    u16* pl = &sP[wv][pb][0];
#pragma unroll
    for (int g = 0; g < 4; ++g) {
      u32 lo = pk_bf16(p[g * 4 + 0], p[g * 4 + 1]);
      u32 hi = pk_bf16(p[g * 4 + 2], p[g * 4 + 3]);
      union { u32 w[2]; u16x4 v; } u;
      u.w[0] = lo; u.w[1] = hi;
      *reinterpret_cast<u16x4*>(pl + l15 * 64 + (((g * 4 + l4) ^ swp) << 2)) = u.v;
    }
  };

  // ---- prologue: stage K(0),V(0),K(1); QK(0); softmax+pack(0) ----
  stageK(0, 0);
  stageV(0, 0);
  stageK(1, 1);
  asm volatile("s_waitcnt vmcnt(0)" ::: "memory");
  __builtin_amdgcn_s_barrier();
  {
    f32x4 sacc[4] = {};
    computeQK(sK[0], sacc);
    softmaxPack(sacc, 0);
  }

  // ---- main loop ----
  for (int t = 0; t < 32; ++t) {
    asm volatile("s_waitcnt vmcnt(0)" ::: "memory");
    __builtin_amdgcn_s_barrier();
    if (t + 2 < 32) stageK(t & 1, t + 2);
    if (t + 1 < 32) stageV((t + 1) & 1, t + 1);

    if (doRescale) {
      float ab[4];
#pragma unroll
      for (int j = 0; j < 4; ++j) ab[j] = __shfl(alphaNext, l4 * 4 + j);
#pragma unroll
      for (int nf = 0; nf < 16; ++nf) {
        oacc[nf][0] *= ab[0]; oacc[nf][1] *= ab[1];
        oacc[nf][2] *= ab[2]; oacc[nf][3] *= ab[3];
      }
    }

    __builtin_amdgcn_s_setprio(1);
    const u16* pl = &sP[wv][t & 1][0];
    const u16* vtile = sVt[t & 1];
#pragma unroll
    for (int c = 0; c < 2; ++c) {
      s16x8 paf = *reinterpret_cast<const s16x8*>(
          pl + l15 * 64 + (((c * 8 + l4 * 2) ^ swp) << 2));
#pragma unroll
      for (int nf = 0; nf < 16; ++nf) {
        s16x8 vf = *reinterpret_cast<const s16x8*>(
            vtile + (nf * 16 + l15) * 64 + (((c * 4 + l4) ^ sw) << 3));
        oacc[nf] = __builtin_amdgcn_mfma_f32_16x16x32_bf16(paf, vf, oacc[nf], 0, 0, 0);
      }
    }
    f32x4 sacc[4] = {};
    if (t + 1 < 32) computeQK(sK[(t + 1) & 1], sacc);
    __builtin_amdgcn_s_setprio(0);

    if (t + 1 < 32) softmaxPack(sacc, (t + 1) & 1);
  }

  // epilogue: O/l, silu(gate), write activation for final GEMM
  float invl = 1.0f / lrow;
  float ib[4];
#pragma unroll
  for (int j = 0; j < 4; ++j) ib[j] = __shfl(invl, l4 * 4 + j);
#pragma unroll
  for (int nf = 0; nf < 16; ++nf) {
#pragma unroll
    for (int j = 0; j < 4; ++j) {
      const int srow = q0 + l4 * 4 + j;
      const int d = nf * 16 + l15;
      float o = oacc[nf][j] * ib[j];
      float g = bf2f(qkv[(size_t)(b * S_N + srow) * QKVW + 2048 + h * 256 + d]);
      float sg = g / (1.0f + __expf(-g));
      act[(size_t)(b * S_N + srow) * 2048 + h * 256 + d] = f2bf(o * sg);
    }
  }
}

extern "C" void kernel_launch(void* const* d_in, const int* in_sizes, int n_in,
                              void* d_out, int out_size, void* d_ws, size_t ws_size,
                              hipStream_t stream) {
  const float* hs  = (const float*)d_in[0];
  const int*   pos = (const int*)d_in[1];
  const float* Wq  = (const float*)d_in[2];
  const float* Wk  = (const float*)d_in[3];
  const float* Wv  = (const float*)d_in[4];
  const float* Wo  = (const float*)d_in[5];
  const float* qw  = (const float*)d_in[6];
  const float* kw  = (const float*)d_in[7];
  float* out = (float*)d_out;

  char* w8 = (char*)d_ws;
  u16* hs_bf   = (u16*)(w8);                    // 8,388,608 B
  u16* wqkv_bf = (u16*)(w8 + 8388608);          // 10,485,760
  u16* wo_bf   = (u16*)(w8 + 18874368);         // 4,194,304
  u16* qkv_raw = (u16*)(w8 + 23068672);         // 41,943,040
  u16* q_r     = (u16*)(w8 + 65011712);         // 16,777,216
  u16* k_r     = (u16*)(w8 + 81788928);         // 4,194,304
  u16* vt      = (u16*)(w8 + 85983232);         // 4,194,304
  u16* act     = (u16*)(w8 + 90177536);         // 16,777,216
  float* cost  = (float*)(w8 + 106954752);      // 262,144
  float* sint  = (float*)(w8 + 107216896);      // 262,144  -> total 107,479,040

  // fused input casts (hs, Wq, Wk, Wv, Wo -> bf16)
  cast5_kernel<<<2048, 256, 0, stream>>>(hs, Wq, Wk, Wv, Wo, hs_bf, wqkv_bf, wo_bf);

  trig_kernel<<<(S_N * 32) / 256, 256, 0, stream>>>(pos, cost, sint);

  // QKV+gate projection: M=4096, N=5120, K=1024 -> qkv_raw bf16
  gemm_bt_kernel<1><<<1280, 256, 0, stream>>>(hs_bf, wqkv_bf, (void*)qkv_raw,
                                              4096, 5120, 1024, 5);

  // RMSNorm + RoPE (q,k); V transpose
  normrope_kernel<<<(B_N * S_N * (H_N + HKV_N)) / 4, 256, 0, stream>>>(
      qkv_raw, qw, kw, cost, sint, q_r, k_r);
  vtrans_kernel<<<512, 256, 0, stream>>>(qkv_raw, vt);

  // attention + gating -> act bf16 (r11 pipelined structure)
  attn_kernel<<<256, 512, 0, stream>>>(q_r, k_r, vt, qkv_raw, act);

  // output projection: M=4096, N=1024, K=2048 -> d_out fp32
  gemm_bt_kernel<0><<<256, 256, 0, stream>>>(act, wo_bf, (void*)out,
                                             4096, 1024, 2048, 1);
}

// Round 15
// 219.503 us; speedup vs baseline: 1.6739x; 1.0341x over previous
//
#include <hip/hip_runtime.h>
#include <math.h>

typedef unsigned short u16;
typedef unsigned int   u32;
typedef __attribute__((ext_vector_type(4))) float f32x4;
typedef __attribute__((ext_vector_type(8))) short s16x8;
typedef __attribute__((ext_vector_type(4))) unsigned short u16x4;

#define B_N   2
#define S_N   2048
#define HID_N 1024
#define H_N   8
#define HKV_N 2
#define D_N   256
#define QKVW  5120   // qkv_raw row width: 2048 q | 2048 gate | 512 k | 512 v

__device__ __forceinline__ u16 f2bf(float f) {
  union { float f; u32 u; } x; x.f = f;
  u32 r = x.u + 0x7FFFu + ((x.u >> 16) & 1u);
  return (u16)(r >> 16);
}
__device__ __forceinline__ float bf2f(u16 u) {
  union { u32 u; float f; } x; x.u = ((u32)u) << 16; return x.f;
}
__device__ __forceinline__ u32 pk_bf16(float lo, float hi) {
  u32 r;
  asm("v_cvt_pk_bf16_f32 %0, %1, %2" : "=v"(r) : "v"(lo), "v"(hi));
  return r;
}
__device__ __forceinline__ void gload_lds16(const u16* g, u16* l) {
  __builtin_amdgcn_global_load_lds((const __attribute__((address_space(1))) u32*)g,
                                   (__attribute__((address_space(3))) u32*)l, 16, 0, 0);
}

// ---------------- fused fp32 -> bf16 casts (5 segments) ----------------
#define N4_HS 1048576
#define N4_WQ 1048576
#define N4_WK 131072
#define N4_WV 131072
#define N4_WO 524288
#define N4_TOT (N4_HS + N4_WQ + N4_WK + N4_WV + N4_WO)

__global__ __launch_bounds__(256)
void cast5_kernel(const float* __restrict__ hs, const float* __restrict__ wq,
                  const float* __restrict__ wk, const float* __restrict__ wv,
                  const float* __restrict__ wo, u16* __restrict__ hs_bf,
                  u16* __restrict__ wqkv_bf, u16* __restrict__ wo_bf) {
  int i = blockIdx.x * blockDim.x + threadIdx.x;
  const int stride = gridDim.x * blockDim.x;
  for (; i < N4_TOT; i += stride) {
    const float* src; u16* dst; int k;
    if (i < N4_HS)                         { src = hs; dst = hs_bf; k = i; }
    else if (i < N4_HS + N4_WQ)            { src = wq; dst = wqkv_bf; k = i - N4_HS; }
    else if (i < N4_HS + N4_WQ + N4_WK)    { src = wk; dst = wqkv_bf + 4194304; k = i - (N4_HS + N4_WQ); }
    else if (i < N4_TOT - N4_WO)           { src = wv; dst = wqkv_bf + 4718592; k = i - (N4_HS + N4_WQ + N4_WK); }
    else                                   { src = wo; dst = wo_bf; k = i - (N4_TOT - N4_WO); }
    float4 v = reinterpret_cast<const float4*>(src)[k];
    u16x4 o;
    o.x = f2bf(v.x); o.y = f2bf(v.y); o.z = f2bf(v.z); o.w = f2bf(v.w);
    reinterpret_cast<u16x4*>(dst)[k] = o;
  }
}

// ---------------- RoPE trig table ----------------
__global__ __launch_bounds__(256)
void trig_kernel(const int* __restrict__ pos, float* __restrict__ ct, float* __restrict__ st) {
  int i = blockIdx.x * blockDim.x + threadIdx.x;
  if (i >= S_N * 32) return;
  int s = i >> 5, j = i & 31;
  double inv = exp(-(double)j * (log(1.0e7) / 32.0));
  double ang = (double)pos[s] * inv;
  ct[i] = (float)cos(ang);
  st[i] = (float)sin(ang);
}

// ---------------- bf16 GEMM (r9/r11: BK=64, T2 swizzle, counted vmcnt, XCD remap) ----------------
template <int OUT_BF16>
__global__ __launch_bounds__(256, 2)
void gemm_bt_kernel(const u16* __restrict__ A, const u16* __restrict__ Bw,
                    void* __restrict__ Cout, int M, int N, int K, int bn_per_x) {
  const int x = blockIdx.x & 7;
  const int i0 = blockIdx.x >> 3;
  const int bm = i0 / bn_per_x;
  const int bn = x * bn_per_x + (i0 - bm * bn_per_x);
  const int tid = threadIdx.x;
  const int lane = tid & 63;
  const int wr = tid >> 7;
  const int wc = (tid >> 6) & 1;
  __shared__ u16 sA[2][128 * 64];
  __shared__ u16 sB[2][128 * 64];
  f32x4 acc[4][4] = {};
  const u16* Ab = A + (size_t)(bm << 7) * K;
  const u16* Bb = Bw + (size_t)(bn << 7) * K;
  const int nkt = K >> 6;

  auto stage = [&](int buf, int kt) {
    const int k0 = kt << 6;
#pragma unroll
    for (int i = 0; i < 4; ++i) {
      const int L = i * 256 + tid;
      const int r = L >> 3, s = L & 7;
      gload_lds16(Ab + (size_t)r * K + k0 + ((s ^ (r & 7)) << 3), &sA[buf][L * 8]);
    }
#pragma unroll
    for (int i = 0; i < 4; ++i) {
      const int L = i * 256 + tid;
      const int r = L >> 3, s = L & 7;
      gload_lds16(Bb + (size_t)r * K + k0 + ((s ^ (r & 7)) << 3), &sB[buf][L * 8]);
    }
  };

  stage(0, 0);
  int cur = 0;
  const int ra = (wr << 6) + (lane & 15);
  const int rb = (wc << 6) + (lane & 15);
  const int l4 = (lane >> 4);
  const int sw = lane & 7;
  for (int kt = 0; kt < nkt; ++kt) {
    if (kt + 1 < nkt) {
      stage(cur ^ 1, kt + 1);
      asm volatile("s_waitcnt vmcnt(8)" ::: "memory");
    } else {
      asm volatile("s_waitcnt vmcnt(0)" ::: "memory");
    }
    __builtin_amdgcn_s_barrier();
    const u16* sa = sA[cur];
    const u16* sb = sB[cur];
#pragma unroll
    for (int kk = 0; kk < 2; ++kk) {
      const int sl = ((kk * 4 + l4) ^ sw) << 3;
      s16x8 af[4], bfr[4];
#pragma unroll
      for (int m = 0; m < 4; ++m)
        af[m] = *reinterpret_cast<const s16x8*>(sa + (ra + m * 16) * 64 + sl);
#pragma unroll
      for (int n = 0; n < 4; ++n)
        bfr[n] = *reinterpret_cast<const s16x8*>(sb + (rb + n * 16) * 64 + sl);
#pragma unroll
      for (int m = 0; m < 4; ++m)
#pragma unroll
        for (int n = 0; n < 4; ++n)
          acc[m][n] = __builtin_amdgcn_mfma_f32_16x16x32_bf16(af[m], bfr[n], acc[m][n], 0, 0, 0);
    }
    __builtin_amdgcn_s_barrier();
    cur ^= 1;
  }
  const int row0 = (bm << 7) + (wr << 6) + ((lane >> 4) << 2);
  const int col0 = (bn << 7) + (wc << 6) + (lane & 15);
#pragma unroll
  for (int m = 0; m < 4; ++m)
#pragma unroll
    for (int n = 0; n < 4; ++n)
#pragma unroll
      for (int j = 0; j < 4; ++j) {
        size_t idx = (size_t)(row0 + m * 16 + j) * N + col0 + n * 16;
        if (OUT_BF16) ((u16*)Cout)[idx] = f2bf(acc[m][n][j]);
        else          ((float*)Cout)[idx] = acc[m][n][j];
      }
}

// ---------------- RMSNorm + RoPE for q and k ----------------
__global__ __launch_bounds__(256)
void normrope_kernel(const u16* __restrict__ qkv, const float* __restrict__ qw,
                     const float* __restrict__ kw, const float* __restrict__ ct,
                     const float* __restrict__ st, u16* __restrict__ q_r,
                     u16* __restrict__ k_r) {
  const int lane = threadIdx.x & 63;
  const int row = blockIdx.x * 4 + (threadIdx.x >> 6);
  const int nq = B_N * S_N * H_N;
  const u16* src; u16* dst; const float* w;
  int s;
  if (row < nq) {
    int h = row & 7; int bs = row >> 3; s = bs & (S_N - 1); int b = bs >> 11;
    src = qkv + (size_t)(b * S_N + s) * QKVW + h * 256;
    dst = q_r + ((size_t)(b * H_N + h) * S_N + s) * 256;
    w = qw;
  } else {
    int r2 = row - nq;
    int h = r2 & 1; int bs = r2 >> 1; s = bs & (S_N - 1); int b = bs >> 11;
    src = qkv + (size_t)(b * S_N + s) * QKVW + 4096 + h * 256;
    dst = k_r + ((size_t)(b * HKV_N + h) * S_N + s) * 256;
    w = kw;
  }
  u16x4 xv = *reinterpret_cast<const u16x4*>(src + lane * 4);
  float x0 = bf2f(xv.x), x1 = bf2f(xv.y), x2 = bf2f(xv.z), x3 = bf2f(xv.w);
  float ss = x0 * x0 + x1 * x1 + x2 * x2 + x3 * x3;
#pragma unroll
  for (int off = 1; off < 64; off <<= 1) ss += __shfl_xor(ss, off);
  float rinv = rsqrtf(ss * (1.0f / 256.0f) + 1e-6f);
  float4 wv = *reinterpret_cast<const float4*>(w + lane * 4);
  float y[4] = { x0 * rinv * wv.x, x1 * rinv * wv.y, x2 * rinv * wv.z, x3 * rinv * wv.w };
  float p[4];
  p[0] = __shfl_xor(y[0], 8);
  p[1] = __shfl_xor(y[1], 8);
  p[2] = __shfl_xor(y[2], 8);
  p[3] = __shfl_xor(y[3], 8);
  if (lane < 16) {
    const float sgn = (lane < 8) ? -1.0f : 1.0f;
    const int jb = (lane * 4) & 31;
#pragma unroll
    for (int e = 0; e < 4; ++e) {
      float c = ct[(size_t)s * 32 + jb + e];
      float sn = st[(size_t)s * 32 + jb + e];
      y[e] = y[e] * c + sgn * p[e] * sn;
    }
  }
  u16x4 ov;
  ov.x = f2bf(y[0]); ov.y = f2bf(y[1]); ov.z = f2bf(y[2]); ov.w = f2bf(y[3]);
  *reinterpret_cast<u16x4*>(dst + lane * 4) = ov;
}

// ---------------- V transpose ----------------
__global__ __launch_bounds__(256)
void vtrans_kernel(const u16* __restrict__ qkv, u16* __restrict__ vt) {
  const int bid = blockIdx.x;            // 512
  const int dt = bid & 3;
  const int stile = (bid >> 2) & 31;
  const int bh = bid >> 7;
  const int b = bh >> 1, kvh = bh & 1;
  __shared__ u16 tile[64][68];
  const int t = threadIdx.x;
  const u16* src = qkv + (size_t)(b * S_N + stile * 64) * QKVW + 4608 + kvh * 256 + dt * 64;
#pragma unroll
  for (int i = 0; i < 2; ++i) {
    int sl = i * 32 + (t >> 3);
    int d8 = (t & 7) * 8;
    s16x8 v = *reinterpret_cast<const s16x8*>(src + (size_t)sl * QKVW + d8);
    u16x4 lo = { (u16)v[0], (u16)v[1], (u16)v[2], (u16)v[3] };
    u16x4 hi = { (u16)v[4], (u16)v[5], (u16)v[6], (u16)v[7] };
    *reinterpret_cast<u16x4*>(&tile[sl][d8]) = lo;
    *reinterpret_cast<u16x4*>(&tile[sl][d8 + 4]) = hi;
  }
  __syncthreads();
#pragma unroll
  for (int i = 0; i < 2; ++i) {
    int dl = i * 32 + (t >> 3);
    int s8 = (t & 7) * 8;
    u16 tmp[8];
#pragma unroll
    for (int e = 0; e < 8; ++e) tmp[e] = tile[s8 + e][dl];
    u16x4 lo = { tmp[0], tmp[1], tmp[2], tmp[3] };
    u16x4 hi = { tmp[4], tmp[5], tmp[6], tmp[7] };
    u16* dstp = vt + ((size_t)(bh * 256 + dt * 64 + dl)) * S_N + stile * 64 + s8;
    *reinterpret_cast<u16x4*>(dstp) = lo;
    *reinterpret_cast<u16x4*>(dstp + 4) = hi;
  }
}

// ---------------- flash attention, cross-step pipelined (r11 verified) ----------------
__global__ __launch_bounds__(512, 2)
void attn_kernel(const u16* __restrict__ q_r, const u16* __restrict__ k_r,
                 const u16* __restrict__ vt, const u16* __restrict__ qkv,
                 u16* __restrict__ act) {
  const int dd = blockIdx.x;             // 0..255
  const int xcd = dd & 7;
  const int idx = dd >> 3;               // 0..31
  const int combo = xcd >> 1;            // b*2+kvh
  const int within = (xcd & 1) * 32 + idx;
  const int b = combo >> 1;
  const int kvh = combo & 1;
  const int h = kvh * 4 + (within >> 4);
  const int qt = within & 15;

  const int tid = threadIdx.x;
  const int lane = tid & 63;
  const int wv = tid >> 6;               // 0..7
  const int l15 = lane & 15;
  const int l4 = lane >> 4;

  __shared__ u16 sK[2][64 * 256];        // [kv][d], swizzled 16B slots (64KB)
  __shared__ u16 sVt[2][256 * 64];       // [d][kv], swizzled (64KB)
  __shared__ u16 sP[8][2][16 * 64];      // per-wave P, dbuf, 8B slots (32KB)

  const int q0 = qt * 128 + wv * 16;
  const u16* qb = q_r + ((size_t)(b * H_N + h) * S_N + q0) * 256;
  s16x8 qf[8];
#pragma unroll
  for (int kk = 0; kk < 8; ++kk)
    qf[kk] = *reinterpret_cast<const s16x8*>(qb + (size_t)l15 * 256 + kk * 32 + l4 * 8);

  f32x4 oacc[16] = {};
  float mrow = -1e30f;
  float lrow = 0.f;

  const u16* kbase = k_r + ((size_t)(b * HKV_N + kvh) * S_N) * 256;
  const u16* vbase = vt + ((size_t)(b * HKV_N + kvh) * 256) * S_N;

  const int krow_b = tid >> 5;           // 0..15
  const int kp = tid & 31;
  const int vrow_b = tid >> 3;           // 0..63
  const int vp = tid & 7;

  auto stageK = [&](int buf, int step) {
    const int kv0 = step << 6;
#pragma unroll
    for (int i = 0; i < 4; ++i) {
      const int krow = i * 16 + krow_b;
      gload_lds16(kbase + (size_t)(kv0 + krow) * 256 + ((kp ^ (krow_b & 7)) << 3),
                  &sK[buf][i * 4096 + tid * 8]);
    }
  };
  auto stageV = [&](int buf, int step) {
    const int kv0 = step << 6;
#pragma unroll
    for (int i = 0; i < 4; ++i) {
      const int vrow = i * 64 + vrow_b;
      gload_lds16(vbase + (size_t)vrow * S_N + kv0 + ((vp ^ (vrow_b & 7)) << 3),
                  &sVt[buf][i * 4096 + tid * 8]);
    }
  };

  const float scale = 0.0625f;  // 1/sqrt(256)
  const int sw = l15 & 7;
  const int swp = l15 & 14;              // even XOR for 8B P slots

  auto computeQK = [&](const u16* ktile, f32x4* sacc) {
#pragma unroll
    for (int kk = 0; kk < 8; ++kk) {
      const int slot = kk * 4 + l4;
#pragma unroll
      for (int g = 0; g < 4; ++g) {
        s16x8 kf = *reinterpret_cast<const s16x8*>(
            ktile + (g * 16 + l15) * 256 + ((slot ^ sw) << 3));
        sacc[g] = __builtin_amdgcn_mfma_f32_16x16x32_bf16(kf, qf[kk], sacc[g], 0, 0, 0);
      }
    }
  };
  float alphaNext = 1.0f;
  int doRescale = 0;
  auto softmaxPack = [&](f32x4* sacc, int pb) {
    float vmax = sacc[0][0];
#pragma unroll
    for (int g = 0; g < 4; ++g)
#pragma unroll
      for (int j = 0; j < 4; ++j) vmax = fmaxf(vmax, sacc[g][j]);
    vmax = fmaxf(vmax, __shfl_xor(vmax, 16));
    vmax = fmaxf(vmax, __shfl_xor(vmax, 32));
    doRescale = __any(vmax > mrow) ? 1 : 0;
    if (doRescale) {
      float mnew = fmaxf(mrow, vmax);
      alphaNext = __expf((mrow - mnew) * scale);
      mrow = mnew;
      lrow *= alphaNext;
    } else {
      alphaNext = 1.0f;
    }
    const float msc = mrow * scale;
    float p[16];
#pragma unroll
    for (int g = 0; g < 4; ++g)
#pragma unroll
      for (int j = 0; j < 4; ++j)
        p[g * 4 + j] = __expf(fmaf(sacc[g][j], scale, -msc));
    float r = ((p[0] + p[1]) + (p[2] + p[3])) + ((p[4] + p[5]) + (p[6] + p[7]))
            + ((p[8] + p[9]) + (p[10] + p[11])) + ((p[12] + p[13]) + (p[14] + p[15]));
    r += __shfl_xor(r, 16);
    r += __shfl_xor(r, 32);
    lrow += r;
    u16* pl = &sP[wv][pb][0];
#pragma unroll
    for (int g = 0; g < 4; ++g) {
      u32 lo = pk_bf16(p[g * 4 + 0], p[g * 4 + 1]);
      u32 hi = pk_bf16(p[g * 4 + 2], p[g * 4 + 3]);
      union { u32 w[2]; u16x4 v; } u;
      u.w[0] = lo; u.w[1] = hi;
      *reinterpret_cast<u16x4*>(pl + l15 * 64 + (((g * 4 + l4) ^ swp) << 2)) = u.v;
    }
  };

  // ---- prologue: stage K(0),V(0),K(1); QK(0); softmax+pack(0) ----
  stageK(0, 0);
  stageV(0, 0);
  stageK(1, 1);
  asm volatile("s_waitcnt vmcnt(0)" ::: "memory");
  __builtin_amdgcn_s_barrier();
  {
    f32x4 sacc[4] = {};
    computeQK(sK[0], sacc);
    softmaxPack(sacc, 0);
  }

  // ---- main loop ----
  for (int t = 0; t < 32; ++t) {
    asm volatile("s_waitcnt vmcnt(0)" ::: "memory");
    __builtin_amdgcn_s_barrier();
    if (t + 2 < 32) stageK(t & 1, t + 2);
    if (t + 1 < 32) stageV((t + 1) & 1, t + 1);

    if (doRescale) {
      float ab[4];
#pragma unroll
      for (int j = 0; j < 4; ++j) ab[j] = __shfl(alphaNext, l4 * 4 + j);
#pragma unroll
      for (int nf = 0; nf < 16; ++nf) {
        oacc[nf][0] *= ab[0]; oacc[nf][1] *= ab[1];
        oacc[nf][2] *= ab[2]; oacc[nf][3] *= ab[3];
      }
    }

    __builtin_amdgcn_s_setprio(1);
    const u16* pl = &sP[wv][t & 1][0];
    const u16* vtile = sVt[t & 1];
#pragma unroll
    for (int c = 0; c < 2; ++c) {
      s16x8 paf = *reinterpret_cast<const s16x8*>(
          pl + l15 * 64 + (((c * 8 + l4 * 2) ^ swp) << 2));
#pragma unroll
      for (int nf = 0; nf < 16; ++nf) {
        s16x8 vf = *reinterpret_cast<const s16x8*>(
            vtile + (nf * 16 + l15) * 64 + (((c * 4 + l4) ^ sw) << 3));
        oacc[nf] = __builtin_amdgcn_mfma_f32_16x16x32_bf16(paf, vf, oacc[nf], 0, 0, 0);
      }
    }
    f32x4 sacc[4] = {};
    if (t + 1 < 32) computeQK(sK[(t + 1) & 1], sacc);
    __builtin_amdgcn_s_setprio(0);

    if (t + 1 < 32) softmaxPack(sacc, (t + 1) & 1);
  }

  // epilogue: O/l, silu(gate), write activation for final GEMM
  float invl = 1.0f / lrow;
  float ib[4];
#pragma unroll
  for (int j = 0; j < 4; ++j) ib[j] = __shfl(invl, l4 * 4 + j);
#pragma unroll
  for (int nf = 0; nf < 16; ++nf) {
#pragma unroll
    for (int j = 0; j < 4; ++j) {
      const int srow = q0 + l4 * 4 + j;
      const int d = nf * 16 + l15;
      float o = oacc[nf][j] * ib[j];
      float g = bf2f(qkv[(size_t)(b * S_N + srow) * QKVW + 2048 + h * 256 + d]);
      float sg = g / (1.0f + __expf(-g));
      act[(size_t)(b * S_N + srow) * 2048 + h * 256 + d] = f2bf(o * sg);
    }
  }
}

extern "C" void kernel_launch(void* const* d_in, const int* in_sizes, int n_in,
                              void* d_out, int out_size, void* d_ws, size_t ws_size,
                              hipStream_t stream) {
  const float* hs  = (const float*)d_in[0];
  const int*   pos = (const int*)d_in[1];
  const float* Wq  = (const float*)d_in[2];
  const float* Wk  = (const float*)d_in[3];
  const float* Wv  = (const float*)d_in[4];
  const float* Wo  = (const float*)d_in[5];
  const float* qw  = (const float*)d_in[6];
  const float* kw  = (const float*)d_in[7];
  float* out = (float*)d_out;

  char* w8 = (char*)d_ws;
  u16* hs_bf   = (u16*)(w8);                    // 8,388,608 B
  u16* wqkv_bf = (u16*)(w8 + 8388608);          // 10,485,760
  u16* wo_bf   = (u16*)(w8 + 18874368);         // 4,194,304
  u16* qkv_raw = (u16*)(w8 + 23068672);         // 41,943,040
  u16* q_r     = (u16*)(w8 + 65011712);         // 16,777,216
  u16* k_r     = (u16*)(w8 + 81788928);         // 4,194,304
  u16* vt      = (u16*)(w8 + 85983232);         // 4,194,304
  u16* act     = (u16*)(w8 + 90177536);         // 16,777,216
  float* cost  = (float*)(w8 + 106954752);      // 262,144
  float* sint  = (float*)(w8 + 107216896);      // 262,144  -> total 107,479,040

  // fused input casts (hs, Wq, Wk, Wv, Wo -> bf16)
  cast5_kernel<<<2048, 256, 0, stream>>>(hs, Wq, Wk, Wv, Wo, hs_bf, wqkv_bf, wo_bf);

  trig_kernel<<<(S_N * 32) / 256, 256, 0, stream>>>(pos, cost, sint);

  // QKV+gate projection: M=4096, N=5120, K=1024 -> qkv_raw bf16
  gemm_bt_kernel<1><<<1280, 256, 0, stream>>>(hs_bf, wqkv_bf, (void*)qkv_raw,
                                              4096, 5120, 1024, 5);

  // RMSNorm + RoPE (q,k); V transpose
  normrope_kernel<<<(B_N * S_N * (H_N + HKV_N)) / 4, 256, 0, stream>>>(
      qkv_raw, qw, kw, cost, sint, q_r, k_r);
  vtrans_kernel<<<512, 256, 0, stream>>>(qkv_raw, vt);

  // attention + gating -> act bf16 (r11 pipelined structure)
  attn_kernel<<<256, 512, 0, stream>>>(q_r, k_r, vt, qkv_raw, act);

  // output projection: M=4096, N=1024, K=2048 -> d_out fp32
  gemm_bt_kernel<0><<<256, 256, 0, stream>>>(act, wo_bf, (void*)out,
                                             4096, 1024, 2048, 1);
}